// Round 1
// baseline (442.638 us; speedup 1.0000x reference)
//
#include <hip/hip_runtime.h>

// GCN, 2 layers, in-dim 1, scalar-per-node propagation (verified R3-R5):
//   deg[c] = 1 + indeg(c); dinv = rsqrt(deg)
//   S[c]   = dinv[c] * ( xd[c] + sum_{(r,c)} xd[r] ),  xd = dinv*x
//   td[r]  = dinv[r] * sum_f relu(b1[f] + W1[f]*S[r]) * W2[f]
//   y[c]   = clip( b2 + dinv[c] * ( td[c] + sum_{(r,c)} td[r] ), -0.5, 9.5 )
//
// R6 (this round, no counters — acquisition timeout):
//   (1) reorder no longer re-reads col to build its local histogram; local
//       counts are reconstructed as H[c+1][b]-H[c][b] (T[b] for last chunk).
//       Saves 64MB HBM + 8192 LDS atomics/block + one sync round.
//   (2) reorder scatter phase reads col/row as int4 (chunk base is 8192-aligned).
//   (3) gcn_count uses u32 LDS atomics (native add, deterministic), float on flush.

#define SZ      2048
#define BSHIFT  11
#define BMASK   2047u
#define ROWBITS 21
#define ROWMASK ((1u << ROWBITS) - 1u)
#define CHUNK   8192

// ---------- phase 1: per-chunk histogram (int4) ----------
__global__ __launch_bounds__(256) void gcn_hist(const int* __restrict__ col,
                                                unsigned* __restrict__ H, int e) {
    __shared__ unsigned h[256];
    int c = blockIdx.x, tid = threadIdx.x;
    int lo = c * CHUNK, hi = min(e, lo + CHUNK);
    h[tid] = 0u;
    __syncthreads();
    int nv = (hi - lo) >> 2;
    const int4* cv = (const int4*)(col + lo);
    for (int k = tid; k < nv; k += 256) {
        int4 v = cv[k];
        atomicAdd(&h[((unsigned)v.x) >> BSHIFT], 1u);
        atomicAdd(&h[((unsigned)v.y) >> BSHIFT], 1u);
        atomicAdd(&h[((unsigned)v.z) >> BSHIFT], 1u);
        atomicAdd(&h[((unsigned)v.w) >> BSHIFT], 1u);
    }
    for (int i = lo + (nv << 2) + tid; i < hi; i += 256)
        atomicAdd(&h[((unsigned)col[i]) >> BSHIFT], 1u);
    __syncthreads();
    H[(size_t)c * 256 + tid] = h[tid];
}

// ---------- phase 2a: per-bucket scan over chunks (H -> exclusive offsets, T totals) ----------
__global__ __launch_bounds__(256) void gcn_scan1(unsigned* __restrict__ H,
                                                 unsigned* __restrict__ T, int C) {
    int b = blockIdx.x, tid = threadIdx.x;
    int L = (C + 255) / 256;
    int c0 = tid * L;
    unsigned partial = 0;
    for (int k = 0; k < L; ++k) {
        int c = c0 + k;
        if (c < C) partial += H[(size_t)c * 256 + b];
    }
    __shared__ unsigned s[256];
    s[tid] = partial;
    __syncthreads();
    for (int off = 1; off < 256; off <<= 1) {
        unsigned t = (tid >= off) ? s[tid - off] : 0u;
        __syncthreads();
        s[tid] += t;
        __syncthreads();
    }
    unsigned run = s[tid] - partial;
    for (int k = 0; k < L; ++k) {
        int c = c0 + k;
        if (c < C) {
            unsigned tmp = H[(size_t)c * 256 + b];
            H[(size_t)c * 256 + b] = run;
            run += tmp;
        }
    }
    if (tid == 255) T[b] = s[255];
}

// ---------- phase 2b: bucket-level exclusive scan ----------
__global__ __launch_bounds__(256) void gcn_scan2(const unsigned* __restrict__ T,
                                                 unsigned* __restrict__ S) {
    int tid = threadIdx.x;
    __shared__ unsigned s[256];
    unsigned v = T[tid];
    s[tid] = v;
    __syncthreads();
    for (int off = 1; off < 256; off <<= 1) {
        unsigned t = (tid >= off) ? s[tid - off] : 0u;
        __syncthreads();
        s[tid] += t;
        __syncthreads();
    }
    S[tid] = s[tid] - v;
}

// ---------- phase 3: local bucket-sort + coalesced write ----------
// Local per-chunk histogram reconstructed from scanned H (and T for last chunk):
// no col re-read, no LDS atomic hist phase.
__global__ __launch_bounds__(512) void gcn_reorder(const int* __restrict__ row,
                                                   const int* __restrict__ col,
                                                   const unsigned* __restrict__ H,
                                                   const unsigned* __restrict__ T,
                                                   const unsigned* __restrict__ S,
                                                   unsigned* __restrict__ sorted,
                                                   int e, int C) {
    __shared__ unsigned keys[CHUNK];
    __shared__ unsigned hist[256], scanL[256], cnt[256], baseG[256];
    int c = blockIdx.x, tid = threadIdx.x;
    int lo = c * CHUNK, hi = min(e, lo + CHUNK), m = hi - lo;
    if (tid < 256) {
        unsigned h0 = H[(size_t)c * 256 + tid];
        unsigned h1 = (c + 1 < C) ? H[(size_t)(c + 1) * 256 + tid] : T[tid];
        unsigned lc = h1 - h0;          // this chunk's count for bucket tid
        hist[tid]  = lc;
        scanL[tid] = lc;
        cnt[tid]   = 0u;
        baseG[tid] = S[tid] + h0;       // global segment base for (chunk, bucket)
    }
    __syncthreads();
    for (int off = 1; off < 256; off <<= 1) {
        unsigned t = 0u;
        if (tid < 256 && tid >= off) t = scanL[tid - off];
        __syncthreads();
        if (tid < 256) scanL[tid] += t;
        __syncthreads();
    }
    if (tid < 256) { scanL[tid] -= hist[tid]; baseG[tid] -= scanL[tid]; }
    __syncthreads();
    // scatter into keys (int4 loads; chunk base is 8192-aligned)
    int nv = m >> 2;
    const int4* cv = (const int4*)(col + lo);
    const int4* rv = (const int4*)(row + lo);
    for (int k = tid; k < nv; k += 512) {
        int4 cc = cv[k];
        int4 rr = rv[k];
        unsigned b, r;
        b = ((unsigned)cc.x) >> BSHIFT; r = scanL[b] + atomicAdd(&cnt[b], 1u);
        keys[r] = ((((unsigned)cc.x) & BMASK) << ROWBITS) | (unsigned)rr.x;
        b = ((unsigned)cc.y) >> BSHIFT; r = scanL[b] + atomicAdd(&cnt[b], 1u);
        keys[r] = ((((unsigned)cc.y) & BMASK) << ROWBITS) | (unsigned)rr.y;
        b = ((unsigned)cc.z) >> BSHIFT; r = scanL[b] + atomicAdd(&cnt[b], 1u);
        keys[r] = ((((unsigned)cc.z) & BMASK) << ROWBITS) | (unsigned)rr.z;
        b = ((unsigned)cc.w) >> BSHIFT; r = scanL[b] + atomicAdd(&cnt[b], 1u);
        keys[r] = ((((unsigned)cc.w) & BMASK) << ROWBITS) | (unsigned)rr.w;
    }
    for (int i = lo + (nv << 2) + tid; i < hi; i += 512) {
        unsigned cvv = (unsigned)col[i];
        unsigned b = cvv >> BSHIFT;
        unsigned r = scanL[b] + atomicAdd(&cnt[b], 1u);
        keys[r] = ((cvv & BMASK) << ROWBITS) | (unsigned)row[i];
    }
    __syncthreads();
    for (int j = tid; j < m; j += 512) {
        // largest b in [0,255] with scanL[b] <= j  (ranks are bucket-contiguous)
        int lo2 = 0, hi2 = 255;
        #pragma unroll
        for (int it = 0; it < 8; ++it) {
            int mid = (lo2 + hi2 + 1) >> 1;
            if (scanL[mid] <= (unsigned)j) lo2 = mid; else hi2 = mid - 1;
        }
        sorted[baseG[lo2] + j] = keys[j];
    }
}

// ---------- consume: 2 blocks per bucket -> private partials (coalesced flush) ----------
__global__ __launch_bounds__(1024) void gcn_count(const unsigned* __restrict__ sorted,
                                                  const unsigned* __restrict__ S,
                                                  float* __restrict__ P, int npad, int e) {
    __shared__ unsigned acc[SZ];
    int b = blockIdx.x >> 1, g = blockIdx.x & 1, tid = threadIdx.x;
    for (int i = tid; i < SZ; i += 1024) acc[i] = 0u;
    __syncthreads();
    int lo = S[b];
    int hi = (b + 1 < 256) ? (int)S[b + 1] : e;
    int half = (hi - lo + 1) >> 1;
    int mylo = lo + g * half, myhi = min(hi, mylo + half);
    int i0 = min((mylo + 3) & ~3, myhi);
    for (int i = mylo + tid; i < i0; i += 1024)
        atomicAdd(&acc[sorted[i] >> ROWBITS], 1u);
    int nv = (myhi - i0) >> 2;
    const uint4* sv = (const uint4*)(sorted + i0);
    for (int k = tid; k < nv; k += 1024) {
        uint4 v = sv[k];
        atomicAdd(&acc[v.x >> ROWBITS], 1u);
        atomicAdd(&acc[v.y >> ROWBITS], 1u);
        atomicAdd(&acc[v.z >> ROWBITS], 1u);
        atomicAdd(&acc[v.w >> ROWBITS], 1u);
    }
    for (int i = i0 + (nv << 2) + tid; i < myhi; i += 1024)
        atomicAdd(&acc[sorted[i] >> ROWBITS], 1u);
    __syncthreads();
    size_t off = (size_t)g * npad + (size_t)b * SZ;
    for (int i = tid; i < SZ; i += 1024) P[off + i] = (float)acc[i];
}

__global__ __launch_bounds__(1024) void gcn_gather(const unsigned* __restrict__ sorted,
                                                   const unsigned* __restrict__ S,
                                                   const float* __restrict__ src,
                                                   float* __restrict__ P, int npad, int e) {
    __shared__ float acc[SZ];
    int b = blockIdx.x >> 1, g = blockIdx.x & 1, tid = threadIdx.x;
    for (int i = tid; i < SZ; i += 1024) acc[i] = 0.0f;
    __syncthreads();
    int lo = S[b];
    int hi = (b + 1 < 256) ? (int)S[b + 1] : e;
    int half = (hi - lo + 1) >> 1;
    int mylo = lo + g * half, myhi = min(hi, mylo + half);
    int i0 = min((mylo + 3) & ~3, myhi);
    for (int i = mylo + tid; i < i0; i += 1024) {
        unsigned p = sorted[i];
        atomicAdd(&acc[p >> ROWBITS], src[p & ROWMASK]);
    }
    int nv = (myhi - i0) >> 2;
    const uint4* sv = (const uint4*)(sorted + i0);
    for (int k = tid; k < nv; k += 1024) {
        uint4 v = sv[k];
        float a = src[v.x & ROWMASK];
        float bb = src[v.y & ROWMASK];
        float cc = src[v.z & ROWMASK];
        float dd = src[v.w & ROWMASK];
        atomicAdd(&acc[v.x >> ROWBITS], a);
        atomicAdd(&acc[v.y >> ROWBITS], bb);
        atomicAdd(&acc[v.z >> ROWBITS], cc);
        atomicAdd(&acc[v.w >> ROWBITS], dd);
    }
    for (int i = i0 + (nv << 2) + tid; i < myhi; i += 1024) {
        unsigned p = sorted[i];
        atomicAdd(&acc[p >> ROWBITS], src[p & ROWMASK]);
    }
    __syncthreads();
    size_t off = (size_t)g * npad + (size_t)b * SZ;
    for (int i = tid; i < SZ; i += 1024) P[off + i] = acc[i];
}

// ---------- node-parallel combines ----------
__global__ __launch_bounds__(256) void gcn_comb0(const float* __restrict__ P, int npad,
                                                 const float* __restrict__ x,
                                                 float* __restrict__ dinv,
                                                 float* __restrict__ xd, int n) {
    int i = blockIdx.x * 256 + threadIdx.x;
    if (i < n) {
        float d = rsqrtf(1.0f + P[i] + P[(size_t)npad + i]);
        dinv[i] = d;
        xd[i] = d * x[i];
    }
}

__global__ __launch_bounds__(256) void gcn_comb1(const float* __restrict__ P, int npad,
                                                 const float* __restrict__ dinv,
                                                 float* __restrict__ xd,   // in: xd, out: td
                                                 const float* __restrict__ W1,
                                                 const float* __restrict__ b1,
                                                 const float* __restrict__ W2, int n) {
    int i = blockIdx.x * 256 + threadIdx.x;
    if (i < n) {
        float d = dinv[i];
        float Sv = d * (P[i] + P[(size_t)npad + i] + xd[i]);
        float t = 0.0f;
        #pragma unroll
        for (int f = 0; f < 10; ++f) {
            float h = fmaf(W1[f], Sv, b1[f]);
            h = h > 0.0f ? h : 0.0f;
            t = fmaf(h, W2[f], t);
        }
        xd[i] = d * t;
    }
}

__global__ __launch_bounds__(256) void gcn_comb2(const float* __restrict__ P, int npad,
                                                 const float* __restrict__ dinv,
                                                 const float* __restrict__ td,
                                                 const float* __restrict__ b2,
                                                 float* __restrict__ out, int n) {
    int i = blockIdx.x * 256 + threadIdx.x;
    if (i < n) {
        float y = b2[0] + dinv[i] * (P[i] + P[(size_t)npad + i] + td[i]);
        out[i] = fminf(fmaxf(y, -0.5f), 9.5f);
    }
}

// ---------------- fallback path (R3, passing) ----------------
__global__ void gcn_init(float* deg, float* acc1, float* acc2, int n) {
    int i = blockIdx.x * blockDim.x + threadIdx.x;
    if (i < n) { deg[i] = 1.0f; acc1[i] = 0.0f; acc2[i] = 0.0f; }
}
__global__ void gcn_deg(const int* col, float* deg, int e) {
    int i = blockIdx.x * blockDim.x + threadIdx.x;
    if (i < e) atomicAdd(&deg[col[i]], 1.0f);
}
__global__ void gcn_dinv(const float* x, float* deg_dinv, float* xd, int n) {
    int i = blockIdx.x * blockDim.x + threadIdx.x;
    if (i < n) { float d = rsqrtf(deg_dinv[i]); deg_dinv[i] = d; xd[i] = d * x[i]; }
}
__global__ void gcn_scatter(const int* row, const int* col, const float* v, float* acc, int e) {
    int i = blockIdx.x * blockDim.x + threadIdx.x;
    if (i < e) atomicAdd(&acc[col[i]], v[row[i]]);
}
__global__ void gcn_mid(const float* dinv, const float* xd, float* acc1_td,
                        const float* W1, const float* b1, const float* W2, int n) {
    int i = blockIdx.x * blockDim.x + threadIdx.x;
    if (i < n) {
        float d = dinv[i];
        float Sv = d * (acc1_td[i] + xd[i]);
        float t = 0.0f;
        #pragma unroll
        for (int f = 0; f < 10; ++f) {
            float h = fmaf(W1[f], Sv, b1[f]);
            h = h > 0.0f ? h : 0.0f;
            t = fmaf(h, W2[f], t);
        }
        acc1_td[i] = d * t;
    }
}
__global__ void gcn_final(const float* dinv, const float* td, const float* b2,
                          float* out_acc2, int n) {
    int i = blockIdx.x * blockDim.x + threadIdx.x;
    if (i < n) {
        float y = b2[0] + dinv[i] * (out_acc2[i] + td[i]);
        out_acc2[i] = fminf(fmaxf(y, -0.5f), 9.5f);
    }
}

extern "C" void kernel_launch(void* const* d_in, const int* in_sizes, int n_in,
                              void* d_out, int out_size, void* d_ws, size_t ws_size,
                              hipStream_t stream) {
    const float* x  = (const float*)d_in[0];
    const int*   ei = (const int*)d_in[1];     // int32 per harness convention
    const float* W1 = (const float*)d_in[2];
    const float* b1 = (const float*)d_in[3];
    const float* W2 = (const float*)d_in[4];
    const float* b2 = (const float*)d_in[5];

    const int n = in_sizes[0];
    const int e = in_sizes[1] / 2;
    const int* row = ei;
    const int* col = ei + e;
    float* out = (float*)d_out;

    const int nb = (n + SZ - 1) / SZ;           // buckets (245)
    const int C  = (e + CHUNK - 1) / CHUNK;     // chunks (1954)
    const int npad = nb * SZ;

    // ws: sorted u32[e] | dinv f32[n] | xd f32[n] | P f32[2*npad] (H aliases) | T[256] S[256]
    size_t need = (size_t)4 * e + (size_t)8 * n + (size_t)8 * npad + 4096;
    bool hFits = (size_t)C * 256 <= (size_t)2 * npad;

    if (ws_size >= need && nb <= 256 && (unsigned)n <= ROWMASK && hFits) {
        unsigned* sorted = (unsigned*)d_ws;
        float*    dinv   = (float*)(sorted + e);
        float*    xd     = dinv + n;
        float*    P      = xd + n;              // 2*npad floats
        unsigned* H      = (unsigned*)P;        // lifetime ends at reorder
        unsigned* T      = (unsigned*)(P + (size_t)2 * npad);
        unsigned* S      = T + 256;

        const int gn = (n + 255) / 256;

        gcn_hist   <<<C,      256, 0, stream>>>(col, H, e);
        gcn_scan1  <<<256,    256, 0, stream>>>(H, T, C);
        gcn_scan2  <<<1,      256, 0, stream>>>(T, S);
        gcn_reorder<<<C,      512, 0, stream>>>(row, col, H, T, S, sorted, e, C);
        gcn_count  <<<nb * 2, 1024, 0, stream>>>(sorted, S, P, npad, e);
        gcn_comb0  <<<gn,     256, 0, stream>>>(P, npad, x, dinv, xd, n);
        gcn_gather <<<nb * 2, 1024, 0, stream>>>(sorted, S, xd, P, npad, e);
        gcn_comb1  <<<gn,     256, 0, stream>>>(P, npad, dinv, xd, W1, b1, W2, n);
        gcn_gather <<<nb * 2, 1024, 0, stream>>>(sorted, S, xd, P, npad, e);
        gcn_comb2  <<<gn,     256, 0, stream>>>(P, npad, dinv, xd, b2, out, n);
    } else {
        float* deg_dinv = (float*)d_ws;
        float* xd       = deg_dinv + n;
        float* acc1     = deg_dinv + 2 * (size_t)n;
        const int B = 256;
        const int gn = (n + B - 1) / B;
        const int ge = (e + B - 1) / B;
        gcn_init   <<<gn, B, 0, stream>>>(deg_dinv, acc1, out, n);
        gcn_deg    <<<ge, B, 0, stream>>>(col, deg_dinv, e);
        gcn_dinv   <<<gn, B, 0, stream>>>(x, deg_dinv, xd, n);
        gcn_scatter<<<ge, B, 0, stream>>>(row, col, xd, acc1, e);
        gcn_mid    <<<gn, B, 0, stream>>>(deg_dinv, xd, acc1, W1, b1, W2, n);
        gcn_scatter<<<ge, B, 0, stream>>>(row, col, acc1, out, e);
        gcn_final  <<<gn, B, 0, stream>>>(deg_dinv, acc1, b2, out, n);
    }
}